// Round 2
// baseline (125.725 us; speedup 1.0000x reference)
//
#include <hip/hip_runtime.h>
#include <hip/hip_bf16.h>
#include <math.h>

#define IMG_H 1024
#define IMG_W 1024
#define NBATCH 32
#define NXCD 8

// One block per (batch,row). 256 threads, each handles 4 consecutive pixels.
// blockIdx is XCD-swizzled so each XCD owns a contiguous band of rows:
// consecutive rows (which share input lines) then hit the same per-XCD L2.
__global__ __launch_bounds__(256) void keypoint_kernel(
    const float* __restrict__ in, float* __restrict__ kp_out,
    float* __restrict__ conf_out) {
  // 32768 blocks total; blocks round-robin XCDs by blockIdx%8, so
  // row = (blockIdx%8)*4096 + blockIdx/8 gives XCD k rows [k*4096, (k+1)*4096).
  const int row = (blockIdx.x & (NXCD - 1)) * ((NBATCH * IMG_H) / NXCD)
                + (blockIdx.x >> 3);
  const int b = row >> 10;             // /IMG_H
  const int y = row & (IMG_H - 1);
  const size_t img_off = (size_t)b * IMG_H * IMG_W;
  const float* img = in + img_off;

  const int x0 = threadIdx.x << 2;     // 4 px per thread
  const float* rc = img + (size_t)y * IMG_W + x0;

  // center row
  const float4 c = *(const float4*)rc;
  float vm1 = (x0 > 0) ? rc[-1] : -INFINITY;
  float v0 = c.x, v1 = c.y, v2 = c.z, v3 = c.w;
  float v4 = (x0 + 4 < IMG_W) ? rc[4] : -INFINITY;

  // row above
  if (y > 0) {
    const float* ru = rc - IMG_W;
    const float4 t = *(const float4*)ru;
    if (x0 > 0) vm1 = fmaxf(vm1, ru[-1]);
    v0 = fmaxf(v0, t.x); v1 = fmaxf(v1, t.y);
    v2 = fmaxf(v2, t.z); v3 = fmaxf(v3, t.w);
    if (x0 + 4 < IMG_W) v4 = fmaxf(v4, ru[4]);
  }
  // row below
  if (y < IMG_H - 1) {
    const float* rd = rc + IMG_W;
    const float4 t = *(const float4*)rd;
    if (x0 > 0) vm1 = fmaxf(vm1, rd[-1]);
    v0 = fmaxf(v0, t.x); v1 = fmaxf(v1, t.y);
    v2 = fmaxf(v2, t.z); v3 = fmaxf(v3, t.w);
    if (x0 + 4 < IMG_W) v4 = fmaxf(v4, rd[4]);
  }

  // horizontal 3-max -> pooled
  const float p0 = fmaxf(fmaxf(vm1, v0), v1);
  const float p1 = fmaxf(fmaxf(v0, v1), v2);
  const float p2 = fmaxf(fmaxf(v1, v2), v3);
  const float p3 = fmaxf(fmaxf(v2, v3), v4);

  const float THR = 0.3f;
  const bool k0 = (p0 == c.x) && (c.x > THR);
  const bool k1 = (p1 == c.y) && (c.y > THR);
  const bool k2 = (p2 == c.z) && (c.z > THR);
  const bool k3 = (p3 == c.w) && (c.w > THR);

  float4 kv, cv;
  kv.x = k0 ? 1.0f : 0.0f; kv.y = k1 ? 1.0f : 0.0f;
  kv.z = k2 ? 1.0f : 0.0f; kv.w = k3 ? 1.0f : 0.0f;
  cv.x = k0 ? c.x : 0.0f;  cv.y = k1 ? c.y : 0.0f;
  cv.z = k2 ? c.z : 0.0f;  cv.w = k3 ? c.w : 0.0f;

  const size_t o = img_off + (size_t)y * IMG_W + x0;
  *(float4*)(kp_out + o)   = kv;
  *(float4*)(conf_out + o) = cv;
}

extern "C" void kernel_launch(void* const* d_in, const int* in_sizes, int n_in,
                              void* d_out, int out_size, void* d_ws, size_t ws_size,
                              hipStream_t stream) {
  const float* in = (const float*)d_in[0];
  float* out = (float*)d_out;
  const size_t plane = (size_t)NBATCH * IMG_H * IMG_W;  // 33554432
  float* kp_out = out;
  float* conf_out = out + plane;
  const int nblocks = NBATCH * IMG_H;  // 32768 (divisible by 8 -> swizzle bijective)
  keypoint_kernel<<<nblocks, 256, 0, stream>>>(in, kp_out, conf_out);
}

// Round 3
// 85.154 us; speedup vs baseline: 1.4764x; 1.4764x over previous
//
#include <hip/hip_runtime.h>
#include <hip/hip_bf16.h>
#include <math.h>

#define IMG_H 1024
#define IMG_W 1024
#define NBATCH 32
#define RPB 16                 // rows per block
#define BANDS (IMG_H / RPB)    // 64

#define MAX3(a, b, c) fmaxf(fmaxf((a), (b)), (c))

// One block per (batch, 16-row band). 256 threads; thread t owns columns
// [4t, 4t+4) for all 16 rows. Rolling prev/cur/next rows in registers:
// each input row is loaded exactly once per block -> halo inflation 1.125x
// regardless of XCD L2 sharing.
__global__ __launch_bounds__(256) void keypoint_kernel(
    const float* __restrict__ in, float* __restrict__ kp_out,
    float* __restrict__ conf_out) {
  const int band = blockIdx.x & (BANDS - 1);
  const int b = blockIdx.x >> 6;       // / BANDS
  const int y0 = band * RPB;
  const size_t img_off = (size_t)b * IMG_H * IMG_W;
  const float* img = in + img_off;

  const int x0 = threadIdx.x << 2;     // 4 px per thread
  const bool has_l = (x0 > 0);
  const bool has_r = (x0 + 4 < IMG_W);

  // prev row (y0-1)
  float4 pr;  float pm1, p4;
  if (y0 > 0) {
    const float* rp = img + (size_t)(y0 - 1) * IMG_W + x0;
    pr = *(const float4*)rp;
    pm1 = has_l ? rp[-1] : -INFINITY;
    p4  = has_r ? rp[4]  : -INFINITY;
  } else {
    pr = make_float4(-INFINITY, -INFINITY, -INFINITY, -INFINITY);
    pm1 = -INFINITY; p4 = -INFINITY;
  }
  // cur row (y0)
  const float* rc0 = img + (size_t)y0 * IMG_W + x0;
  float4 cu = *(const float4*)rc0;
  float cm1 = has_l ? rc0[-1] : -INFINITY;
  float c4  = has_r ? rc0[4]  : -INFINITY;

  const float THR = 0.3f;

  #pragma unroll 4
  for (int r = 0; r < RPB; ++r) {
    const int y = y0 + r;
    // next row (y+1)
    float4 nx;  float nm1, n4;
    if (y + 1 < IMG_H) {
      const float* rn = img + (size_t)(y + 1) * IMG_W + x0;
      nx = *(const float4*)rn;
      nm1 = has_l ? rn[-1] : -INFINITY;
      n4  = has_r ? rn[4]  : -INFINITY;
    } else {
      nx = make_float4(-INFINITY, -INFINITY, -INFINITY, -INFINITY);
      nm1 = -INFINITY; n4 = -INFINITY;
    }

    // vertical 3-max per column (clang fuses to v_max3_f32)
    const float vm1 = MAX3(pm1, cm1, nm1);
    const float v0 = MAX3(pr.x, cu.x, nx.x);
    const float v1 = MAX3(pr.y, cu.y, nx.y);
    const float v2 = MAX3(pr.z, cu.z, nx.z);
    const float v3 = MAX3(pr.w, cu.w, nx.w);
    const float v4 = MAX3(p4, c4, n4);

    // horizontal 3-max -> pooled
    const float q0 = MAX3(vm1, v0, v1);
    const float q1 = MAX3(v0, v1, v2);
    const float q2 = MAX3(v1, v2, v3);
    const float q3 = MAX3(v2, v3, v4);

    const bool k0 = (q0 == cu.x) && (cu.x > THR);
    const bool k1 = (q1 == cu.y) && (cu.y > THR);
    const bool k2 = (q2 == cu.z) && (cu.z > THR);
    const bool k3 = (q3 == cu.w) && (cu.w > THR);

    float4 kv, cv;
    kv.x = k0 ? 1.0f : 0.0f; kv.y = k1 ? 1.0f : 0.0f;
    kv.z = k2 ? 1.0f : 0.0f; kv.w = k3 ? 1.0f : 0.0f;
    cv.x = k0 ? cu.x : 0.0f; cv.y = k1 ? cu.y : 0.0f;
    cv.z = k2 ? cu.z : 0.0f; cv.w = k3 ? cu.w : 0.0f;

    const size_t o = img_off + (size_t)y * IMG_W + x0;
    *(float4*)(kp_out + o)   = kv;
    *(float4*)(conf_out + o) = cv;

    // roll
    pr = cu; cu = nx;
    pm1 = cm1; cm1 = nm1;
    p4 = c4; c4 = n4;
  }
}

extern "C" void kernel_launch(void* const* d_in, const int* in_sizes, int n_in,
                              void* d_out, int out_size, void* d_ws, size_t ws_size,
                              hipStream_t stream) {
  const float* in = (const float*)d_in[0];
  float* out = (float*)d_out;
  const size_t plane = (size_t)NBATCH * IMG_H * IMG_W;  // 33554432
  float* kp_out = out;
  float* conf_out = out + plane;
  const int nblocks = NBATCH * BANDS;  // 2048 = full-machine residency
  keypoint_kernel<<<nblocks, 256, 0, stream>>>(in, kp_out, conf_out);
}

// Round 5
// 64.886 us; speedup vs baseline: 1.9376x; 1.3124x over previous
//
#include <hip/hip_runtime.h>
#include <hip/hip_bf16.h>
#include <math.h>

#define IMG_H 1024
#define IMG_W 1024
#define NBATCH 32
#define RPB 16                 // rows per block
#define BANDS (IMG_H / RPB)    // 64

#define MAX3(a, b, c) fmaxf(fmaxf((a), (b)), (c))

typedef float f32x4 __attribute__((ext_vector_type(4)));  // native vector for nt-store

// One block per (batch, 16-row band). 256 threads; thread t owns columns
// [4t, 4t+4) for all 16 rows. Rolling prev/cur/next rows in registers:
// each input row is loaded exactly once per block -> halo inflation 1.125x.
// Outputs are streamed with nontemporal stores (never re-read) so they do
// not evict the re-read input from L2/L3.
__global__ __launch_bounds__(256) void keypoint_kernel(
    const float* __restrict__ in, float* __restrict__ kp_out,
    float* __restrict__ conf_out) {
  const int band = blockIdx.x & (BANDS - 1);
  const int b = blockIdx.x >> 6;       // / BANDS
  const int y0 = band * RPB;
  const size_t img_off = (size_t)b * IMG_H * IMG_W;
  const float* img = in + img_off;

  const int x0 = threadIdx.x << 2;     // 4 px per thread
  const bool has_l = (x0 > 0);
  const bool has_r = (x0 + 4 < IMG_W);

  // prev row (y0-1)
  float4 pr;  float pm1, p4;
  if (y0 > 0) {
    const float* rp = img + (size_t)(y0 - 1) * IMG_W + x0;
    pr = *(const float4*)rp;
    pm1 = has_l ? rp[-1] : -INFINITY;
    p4  = has_r ? rp[4]  : -INFINITY;
  } else {
    pr = make_float4(-INFINITY, -INFINITY, -INFINITY, -INFINITY);
    pm1 = -INFINITY; p4 = -INFINITY;
  }
  // cur row (y0)
  const float* rc0 = img + (size_t)y0 * IMG_W + x0;
  float4 cu = *(const float4*)rc0;
  float cm1 = has_l ? rc0[-1] : -INFINITY;
  float c4  = has_r ? rc0[4]  : -INFINITY;

  const float THR = 0.3f;

  #pragma unroll 4
  for (int r = 0; r < RPB; ++r) {
    const int y = y0 + r;
    // next row (y+1)
    float4 nx;  float nm1, n4;
    if (y + 1 < IMG_H) {
      const float* rn = img + (size_t)(y + 1) * IMG_W + x0;
      nx = *(const float4*)rn;
      nm1 = has_l ? rn[-1] : -INFINITY;
      n4  = has_r ? rn[4]  : -INFINITY;
    } else {
      nx = make_float4(-INFINITY, -INFINITY, -INFINITY, -INFINITY);
      nm1 = -INFINITY; n4 = -INFINITY;
    }

    // vertical 3-max per column (clang fuses to v_max3_f32)
    const float vm1 = MAX3(pm1, cm1, nm1);
    const float v0 = MAX3(pr.x, cu.x, nx.x);
    const float v1 = MAX3(pr.y, cu.y, nx.y);
    const float v2 = MAX3(pr.z, cu.z, nx.z);
    const float v3 = MAX3(pr.w, cu.w, nx.w);
    const float v4 = MAX3(p4, c4, n4);

    // horizontal 3-max -> pooled
    const float q0 = MAX3(vm1, v0, v1);
    const float q1 = MAX3(v0, v1, v2);
    const float q2 = MAX3(v1, v2, v3);
    const float q3 = MAX3(v2, v3, v4);

    const bool k0 = (q0 == cu.x) && (cu.x > THR);
    const bool k1 = (q1 == cu.y) && (cu.y > THR);
    const bool k2 = (q2 == cu.z) && (cu.z > THR);
    const bool k3 = (q3 == cu.w) && (cu.w > THR);

    f32x4 kv, cv;
    kv.x = k0 ? 1.0f : 0.0f; kv.y = k1 ? 1.0f : 0.0f;
    kv.z = k2 ? 1.0f : 0.0f; kv.w = k3 ? 1.0f : 0.0f;
    cv.x = k0 ? cu.x : 0.0f; cv.y = k1 ? cu.y : 0.0f;
    cv.z = k2 ? cu.z : 0.0f; cv.w = k3 ? cu.w : 0.0f;

    const size_t o = img_off + (size_t)y * IMG_W + x0;
    __builtin_nontemporal_store(kv, (f32x4*)(kp_out + o));
    __builtin_nontemporal_store(cv, (f32x4*)(conf_out + o));

    // roll
    pr = cu; cu = nx;
    pm1 = cm1; cm1 = nm1;
    p4 = c4; c4 = n4;
  }
}

extern "C" void kernel_launch(void* const* d_in, const int* in_sizes, int n_in,
                              void* d_out, int out_size, void* d_ws, size_t ws_size,
                              hipStream_t stream) {
  const float* in = (const float*)d_in[0];
  float* out = (float*)d_out;
  const size_t plane = (size_t)NBATCH * IMG_H * IMG_W;  // 33554432
  float* kp_out = out;
  float* conf_out = out + plane;
  const int nblocks = NBATCH * BANDS;  // 2048 = full-machine residency
  keypoint_kernel<<<nblocks, 256, 0, stream>>>(in, kp_out, conf_out);
}